// Round 3
// baseline (292.539 us; speedup 1.0000x reference)
//
#include <hip/hip_runtime.h>
#include <hip/hip_bf16.h>

// CARAFE fp32 pipeline. x(4,256,64,64), Wc(64,256), bc(64), We(100,64,3,3),
// be(100) -> out(4,256,128,128). SF=2 K=5 G=1 CC=64 EK=3. All I/O fp32.
//
// ws layout (fp32 elements):
//   comp  [4][64][66*66]   zero-padded halo   @ 0          (1,115,136)
//   Wr2   [ij4][kt5][cc64][48]  q*5+kk packed @ 1,115,136  (61,440 of 64,512)
//   logit [16384 px][100]  e = 4k+ij          @ 1,179,648  (1,638,400)
// total 11,272,192 B. Host-gated on ws_size; fallback = fused kernel.
//
// Round 6 (this round): k3 v2. Round-5 post-mortem: k2 fix landed (out of
// top-5); k3 now dominant at 52.5us, HBM 31%, VALUBusy 30%, 3.28M bank
// conflicts -- DS-pipe bound: 400 scalar ds_read_b32 per thread (16c x 25
// taps). v2: channel-PAIR interleaved tile xt[cg8][r20][q20][2], row stride
// 42 words -> one ds_read_b64 per tap covers 2 channels, lanes contiguous
// 8B (conflict-free), tap offsets fold to immediates. 200 b64 vs 400 b32;
// float2 staging loads (halo col origin always even); mk loads hoisted.

#define COMP_F 0
#define WR_F   1115136
#define LOG_F  1179648
#define WS_NEED 11272192ull
#define CSTR 4356  // 66*66 comp per-channel stride

// ---------------- K0: We(100,576) -> Wr2[ij][kt][cc][48] ----------------
// Wr2 row (48 floats, 192B-aligned) holds w[q*5+kk] for one (ij,kt,cc).
__global__ void k0_wr(const float* __restrict__ We, float* __restrict__ ws) {
    int tid = blockIdx.x * blockDim.x + threadIdx.x;
    if (tid >= 4 * 5 * 64 * 45) return;
    int kk = tid % 5;
    int q  = (tid / 5) % 9;
    int cc = (tid / 45) % 64;
    int kt = (tid / 2880) % 5;
    int ij = tid / 14400;
    ws[WR_F + (size_t)(((ij * 5 + kt) * 64 + cc)) * 48 + q * 5 + kk] =
        We[(size_t)(4 * (kt * 5 + kk) + ij) * 576 + cc * 9 + q];
}

// ---------------- K1: 1x1 compressor 256->64, padded comp out ----------
// grid 2048 x 64thr: b = ccg*256 + pw  (same-pixel siblings share XCD L2).
__global__ __launch_bounds__(64) void k1_comp(const float* __restrict__ x,
                                              const float* __restrict__ Wc,
                                              const float* __restrict__ bc,
                                              float* __restrict__ ws) {
    int b   = blockIdx.x;
    int pw  = b & 255;
    int ccg = b >> 8;          // 0..7, wave-uniform
    int n = pw >> 6, h = pw & 63, w = threadIdx.x;
    int cc0 = ccg * 8;

    float acc[8];
#pragma unroll
    for (int u = 0; u < 8; ++u) acc[u] = 0.f;

    const float* xp = x + (size_t)n * 256 * 4096 + h * 64 + w;
#pragma unroll 4
    for (int c = 0; c < 256; ++c) {
        float xv = xp[(size_t)c * 4096];
#pragma unroll
        for (int u = 0; u < 8; ++u)
            acc[u] += xv * Wc[(cc0 + u) * 256 + c];  // uniform -> s_load
    }

    float* compb = ws + COMP_F + (size_t)(n * 64 + cc0) * CSTR;
#pragma unroll
    for (int u = 0; u < 8; ++u) {
        float* cb_ = compb + (size_t)u * CSTR;
        cb_[(h + 1) * 66 + (w + 1)] = acc[u] + bc[cc0 + u];
        // zero halo border (pad=1 of the 3x3 conv)
        if (w < 2) cb_[(h + 1) * 66 + (w ? 65 : 0)] = 0.f;
        if (h == 0)  { cb_[w] = 0.f;           if (w < 2) cb_[64 + w] = 0.f; }
        if (h == 63) { cb_[65 * 66 + w] = 0.f; if (w < 2) cb_[65 * 66 + 64 + w] = 0.f; }
    }
}

// ---------------- K2 v3: 3x3 encoder -> raw logits ----------------------
// grid 1280 = kt*256 + tile; block 256 thr = 4 ij-waves. kt gives k-range
// [kt*5, kt*5+5). comp 8x8 tile + 3x3 halo in LDS, row stride 12 (2-way
// bank aliasing = free). Weights read with wave-uniform addresses from
// global Wr2 -> s_load/SGPR (SMEM pipe), NOT the DS pipe. Per channel:
// 9 ds_read + 45 v_fmac (SGPR weight operand).
__global__ __launch_bounds__(256, 5) void k2_enc(const float* __restrict__ be,
                                                 float* __restrict__ ws) {
    __shared__ __align__(16) float compT[64 * 120];  // 30720 B
    int b    = blockIdx.x;
    int tile = b & 255;                              // low bits: same-tile
    int kt   = b >> 8;                               // 0..4, siblings same XCD
    int n = tile >> 6, th = (tile >> 3) & 7, tw = tile & 7;
    int h0 = th * 8, w0 = tw * 8;
    int tid = threadIdx.x;

    const float* compn = ws + COMP_F + (size_t)n * 64 * CSTR;
    // stage comp halo tile: compT[c*120 + r*12 + q] = comp[c][h0+r][w0+q]
    for (int e = tid; e < 6400; e += 256) {
        int c = e / 100, rq = e % 100, r = rq / 10, q = rq % 10;
        compT[c * 120 + r * 12 + q] =
            compn[(size_t)c * CSTR + (h0 + r) * 66 + (w0 + q)];
    }
    __syncthreads();

    int lane = tid & 63;
    int ij   = __builtin_amdgcn_readfirstlane(tid >> 6);  // force scalar
    int py = lane >> 3, pxx = lane & 7;

    const float* wb = ws + WR_F + (size_t)((ij * 5 + kt) * 64) * 48;

    float acc[5];
#pragma unroll
    for (int kk = 0; kk < 5; ++kk) acc[kk] = be[4 * (kt * 5 + kk) + ij];

#pragma unroll 2
    for (int c = 0; c < 64; ++c) {
        const float* cp = compT + c * 120 + py * 12 + pxx;
        float cv[9];
#pragma unroll
        for (int dy = 0; dy < 3; ++dy)
#pragma unroll
            for (int dx = 0; dx < 3; ++dx)
                cv[dy * 3 + dx] = cp[dy * 12 + dx];
        const float* w = wb + c * 48;                // uniform -> s_load
#pragma unroll
        for (int q = 0; q < 9; ++q) {
            float v = cv[q];
#pragma unroll
            for (int kk = 0; kk < 5; ++kk)
                acc[kk] += v * w[q * 5 + kk];        // v_fmac v, s, v
        }
    }

    float* lp = ws + LOG_F +
                (size_t)(n * 4096 + (h0 + py) * 64 + (w0 + pxx)) * 100 + ij;
#pragma unroll
    for (int kk = 0; kk < 5; ++kk) lp[4 * (kt * 5 + kk)] = acc[kk];
}

// ---------------- K3 v2: softmax (in-reg) + reassembly ------------------
// grid 1024 x 256thr: b = cchunk*64 + tile. 16x16 px tile, 16-c chunk.
// x tile in LDS as [cg8][r20][q20][2] (channel pairs innermost, row stride
// 42 words): one ds_read_b64 per tap serves 2 channels, lanes contiguous
// 8B (conflict-free quarter-wave pattern), tap offsets are immediates.
__global__ __launch_bounds__(256, 4) void k3_out(const float* __restrict__ x,
                                                 const float* __restrict__ ws,
                                                 float* __restrict__ out) {
    __shared__ __align__(16) float xt[8 * 20 * 42];  // 26880 B
    int b      = blockIdx.x;
    int tile   = b & 63;
    int cchunk = b >> 6;
    int n = tile >> 4, ty0 = ((tile >> 2) & 3) * 16, tx0 = (tile & 3) * 16;
    int c0 = cchunk * 16;

    int py = threadIdx.x >> 4, pxx = threadIdx.x & 15;
    int h = ty0 + py, w = tx0 + pxx;

    // issue logit loads first (independent of staging; overlaps)
    const float* lp = ws + LOG_F + (size_t)(n * 4096 + h * 64 + w) * 100;
    float4 mk[25];
#pragma unroll
    for (int t = 0; t < 25; ++t) mk[t] = ((const float4*)lp)[t];

    // stage x halo tile as float2 (halo col origin tx0-2 is even -> the
    // 20-wide row is 10 aligned float2s, all-or-nothing in bounds).
    const float* xn = x + (size_t)(n * 256 + c0) * 4096;
    for (int e2 = threadIdx.x; e2 < 3200; e2 += 256) {
        int c = e2 / 200, rem = e2 % 200, r = rem / 10, q2 = rem % 10;
        int hh = ty0 + r - 2, ww = tx0 + 2 * q2 - 2;
        float2 v = {0.f, 0.f};
        if (hh >= 0 && hh < 64 && ww >= 0 && ww < 64)
            v = *(const float2*)(xn + (size_t)c * 4096 + hh * 64 + ww);
        int a0 = (c >> 1) * 840 + r * 42 + 4 * q2 + (c & 1);
        xt[a0]     = v.x;
        xt[a0 + 2] = v.y;
    }

    // softmax over the 25 taps, per ij component (recomputed per c-chunk: free)
    float4 mx = mk[0];
#pragma unroll
    for (int t = 1; t < 25; ++t) {
        mx.x = fmaxf(mx.x, mk[t].x); mx.y = fmaxf(mx.y, mk[t].y);
        mx.z = fmaxf(mx.z, mk[t].z); mx.w = fmaxf(mx.w, mk[t].w);
    }
    float4 sm = {0.f, 0.f, 0.f, 0.f};
#pragma unroll
    for (int t = 0; t < 25; ++t) {
        mk[t].x = __expf(mk[t].x - mx.x); sm.x += mk[t].x;
        mk[t].y = __expf(mk[t].y - mx.y); sm.y += mk[t].y;
        mk[t].z = __expf(mk[t].z - mx.z); sm.z += mk[t].z;
        mk[t].w = __expf(mk[t].w - mx.w); sm.w += mk[t].w;
    }
    float4 iv = {1.f / sm.x, 1.f / sm.y, 1.f / sm.z, 1.f / sm.w};
#pragma unroll
    for (int t = 0; t < 25; ++t) {
        mk[t].x *= iv.x; mk[t].y *= iv.y; mk[t].z *= iv.z; mk[t].w *= iv.w;
    }
    __syncthreads();

    const float* vb = xt + py * 42 + pxx * 2;
    for (int cg = 0; cg < 8; ++cg) {
        const float* vbc = vb + cg * 840;
        float2 a0 = {0.f, 0.f}, a1 = {0.f, 0.f}, a2 = {0.f, 0.f}, a3 = {0.f, 0.f};
#pragma unroll
        for (int dy = 0; dy < 5; ++dy)
#pragma unroll
            for (int dx = 0; dx < 5; ++dx) {
                int t = dy * 5 + dx;
                float2 v = *(const float2*)(vbc + dy * 42 + dx * 2);
                a0.x += v.x * mk[t].x; a0.y += v.y * mk[t].x;
                a1.x += v.x * mk[t].y; a1.y += v.y * mk[t].y;
                a2.x += v.x * mk[t].z; a2.y += v.y * mk[t].z;
                a3.x += v.x * mk[t].w; a3.y += v.y * mk[t].w;
            }
        int c = cg * 2;
        size_t ob0 = (((size_t)(n * 256 + c0 + c) * 128) + 2 * h) * 128 + 2 * w;
        float2 r0 = {a0.x, a1.x}, r1 = {a2.x, a3.x};
        *(float2*)(out + ob0)       = r0;
        *(float2*)(out + ob0 + 128) = r1;
        size_t ob1 = ob0 + 16384;
        float2 r2 = {a0.y, a1.y}, r3 = {a2.y, a3.y};
        *(float2*)(out + ob1)       = r2;
        *(float2*)(out + ob1 + 128) = r3;
    }
}

// ---------------- Fallback: fused kernel, fp32-only ---------------------
__global__ __launch_bounds__(256) void k_fused(const float* __restrict__ x,
                                               const float* __restrict__ Wc,
                                               const float* __restrict__ bc,
                                               const float* __restrict__ We,
                                               const float* __restrict__ be,
                                               float* __restrict__ out) {
    __shared__ float compS[64 * 101];
    int n = blockIdx.x >> 6, tile = blockIdx.x & 63;
    int ty0 = (tile >> 3) * 8, tx0 = (tile & 7) * 8;
    const float* xn = x + (size_t)n * 256 * 4096;
    {
        int pa = threadIdx.x & 127;
        int ga = __builtin_amdgcn_readfirstlane(threadIdx.x >> 7);
        bool act = pa < 100;
        int ah = ty0 + pa / 10 - 1, aw = tx0 + pa % 10 - 1;
        bool inb = act && ah >= 0 && ah < 64 && aw >= 0 && aw < 64;
        int xoff = ah * 64 + aw;
        float acc[32];
#pragma unroll
        for (int i = 0; i < 32; ++i) acc[i] = 0.f;
        for (int c = 0; c < 256; ++c) {
            float xv = inb ? xn[(size_t)c * 4096 + xoff] : 0.f;
#pragma unroll
            for (int i = 0; i < 32; ++i) acc[i] += xv * Wc[(ga * 32 + i) * 256 + c];
        }
        if (act)
#pragma unroll
            for (int i = 0; i < 32; ++i) {
                int cc = ga * 32 + i;
                compS[cc * 101 + pa] = inb ? acc[i] + bc[cc] : 0.f;
            }
    }
    __syncthreads();
    int px = threadIdx.x & 63;
    int ij = __builtin_amdgcn_readfirstlane(threadIdx.x >> 6);
    int py = px >> 3, pxx = px & 7;
    int h = ty0 + py, w = tx0 + pxx;
    float m[25];
#pragma unroll
    for (int k = 0; k < 25; ++k) m[k] = be[4 * k + ij];
    for (int cc = 0; cc < 64; ++cc) {
        float cv[9];
#pragma unroll
        for (int dy = 0; dy < 3; ++dy)
#pragma unroll
            for (int dx = 0; dx < 3; ++dx)
                cv[dy * 3 + dx] = compS[cc * 101 + (py + dy) * 10 + (pxx + dx)];
        int base = cc * 9;
#pragma unroll
        for (int k = 0; k < 25; ++k) {
            int eb = (4 * k + ij) * 576 + base;
            float s = 0.f;
#pragma unroll
            for (int qb = 0; qb < 9; ++qb) s += cv[qb] * We[eb + qb];
            m[k] += s;
        }
    }
    float mxv = m[0];
#pragma unroll
    for (int k = 1; k < 25; ++k) mxv = fmaxf(mxv, m[k]);
    float ss = 0.f;
#pragma unroll
    for (int k = 0; k < 25; ++k) { m[k] = __expf(m[k] - mxv); ss += m[k]; }
    float inv = 1.f / ss;
#pragma unroll
    for (int k = 0; k < 25; ++k) m[k] *= inv;
    int offs[25];
    unsigned vm = 0;
#pragma unroll
    for (int t = 0; t < 25; ++t) {
        int hh = h + t / 5 - 2, ww = w + t % 5 - 2;
        bool v = hh >= 0 && hh < 64 && ww >= 0 && ww < 64;
        offs[t] = v ? hh * 64 + ww : 0;
        if (v) vm |= 1u << t;
    }
    size_t outp = ((size_t)n * 256 * 128 + (2 * h + (ij >> 1))) * 128 + (2 * w + (ij & 1));
    for (int c = 0; c < 256; ++c) {
        const float* xc = xn + (size_t)c * 4096;
        float sum = 0.f;
#pragma unroll
        for (int t = 0; t < 25; ++t) {
            float v = ((vm >> t) & 1u) ? xc[offs[t]] : 0.f;
            sum += v * m[t];
        }
        out[outp + (size_t)c * 16384] = sum;
    }
}

extern "C" void kernel_launch(void* const* d_in, const int* in_sizes, int n_in,
                              void* d_out, int out_size, void* d_ws, size_t ws_size,
                              hipStream_t stream) {
    const float* x  = (const float*)d_in[0];
    const float* Wc = (const float*)d_in[1];
    const float* bc = (const float*)d_in[2];
    const float* We = (const float*)d_in[3];
    const float* be = (const float*)d_in[4];
    float* out = (float*)d_out;

    if (ws_size >= WS_NEED && d_ws != nullptr) {
        float* ws = (float*)d_ws;
        hipLaunchKernelGGL(k0_wr,   dim3(226),  dim3(256), 0, stream, We, ws);
        hipLaunchKernelGGL(k1_comp, dim3(2048), dim3(64),  0, stream, x, Wc, bc, ws);
        hipLaunchKernelGGL(k2_enc,  dim3(1280), dim3(256), 0, stream, be, ws);
        hipLaunchKernelGGL(k3_out,  dim3(1024), dim3(256), 0, stream, x, ws, out);
    } else {
        hipLaunchKernelGGL(k_fused, dim3(256),  dim3(256), 0, stream,
                           x, Wc, bc, We, be, out);
    }
}

// Round 4
// 273.319 us; speedup vs baseline: 1.0703x; 1.0703x over previous
//
#include <hip/hip_runtime.h>
#include <hip/hip_bf16.h>

// CARAFE fp32 pipeline. x(4,256,64,64), Wc(64,256), bc(64), We(100,64,3,3),
// be(100) -> out(4,256,128,128). SF=2 K=5 G=1 CC=64 EK=3. All I/O fp32.
//
// ws layout (fp32 elements):
//   comp  [4][64][66*66]   zero-padded halo   @ 0          (1,115,136)
//   Wr2   [ij4][kt5][cc64][48]  q*5+kk packed @ 1,115,136  (61,440 of 64,512)
//   logit [16384 px][100]  e = 4k+ij          @ 1,179,648  (1,638,400)
// total 11,272,192 B. Host-gated on ws_size; fallback = fused kernel.
//
// Round 7 (this round): k3 v2 spill fix. Round-6 post-mortem: the v2 tile
// layout worked (bank conflicts 3.28M -> 467K) but __launch_bounds__(256,4)
// capped VGPRs at 64 < the ~130 live (float4 mk[25] alone = 100) -> mk
// spilled to scratch -> 490 MB/dispatch spill traffic, 150us. Fix: bound
// (256,3) = 170-VGPR cap, no spill, 3 blocks/CU. No other changes.

#define COMP_F 0
#define WR_F   1115136
#define LOG_F  1179648
#define WS_NEED 11272192ull
#define CSTR 4356  // 66*66 comp per-channel stride

// ---------------- K0: We(100,576) -> Wr2[ij][kt][cc][48] ----------------
// Wr2 row (48 floats, 192B-aligned) holds w[q*5+kk] for one (ij,kt,cc).
__global__ void k0_wr(const float* __restrict__ We, float* __restrict__ ws) {
    int tid = blockIdx.x * blockDim.x + threadIdx.x;
    if (tid >= 4 * 5 * 64 * 45) return;
    int kk = tid % 5;
    int q  = (tid / 5) % 9;
    int cc = (tid / 45) % 64;
    int kt = (tid / 2880) % 5;
    int ij = tid / 14400;
    ws[WR_F + (size_t)(((ij * 5 + kt) * 64 + cc)) * 48 + q * 5 + kk] =
        We[(size_t)(4 * (kt * 5 + kk) + ij) * 576 + cc * 9 + q];
}

// ---------------- K1: 1x1 compressor 256->64, padded comp out ----------
// grid 2048 x 64thr: b = ccg*256 + pw  (same-pixel siblings share XCD L2).
__global__ __launch_bounds__(64) void k1_comp(const float* __restrict__ x,
                                              const float* __restrict__ Wc,
                                              const float* __restrict__ bc,
                                              float* __restrict__ ws) {
    int b   = blockIdx.x;
    int pw  = b & 255;
    int ccg = b >> 8;          // 0..7, wave-uniform
    int n = pw >> 6, h = pw & 63, w = threadIdx.x;
    int cc0 = ccg * 8;

    float acc[8];
#pragma unroll
    for (int u = 0; u < 8; ++u) acc[u] = 0.f;

    const float* xp = x + (size_t)n * 256 * 4096 + h * 64 + w;
#pragma unroll 4
    for (int c = 0; c < 256; ++c) {
        float xv = xp[(size_t)c * 4096];
#pragma unroll
        for (int u = 0; u < 8; ++u)
            acc[u] += xv * Wc[(cc0 + u) * 256 + c];  // uniform -> s_load
    }

    float* compb = ws + COMP_F + (size_t)(n * 64 + cc0) * CSTR;
#pragma unroll
    for (int u = 0; u < 8; ++u) {
        float* cb_ = compb + (size_t)u * CSTR;
        cb_[(h + 1) * 66 + (w + 1)] = acc[u] + bc[cc0 + u];
        // zero halo border (pad=1 of the 3x3 conv)
        if (w < 2) cb_[(h + 1) * 66 + (w ? 65 : 0)] = 0.f;
        if (h == 0)  { cb_[w] = 0.f;           if (w < 2) cb_[64 + w] = 0.f; }
        if (h == 63) { cb_[65 * 66 + w] = 0.f; if (w < 2) cb_[65 * 66 + 64 + w] = 0.f; }
    }
}

// ---------------- K2 v3: 3x3 encoder -> raw logits ----------------------
// grid 1280 = kt*256 + tile; block 256 thr = 4 ij-waves. kt gives k-range
// [kt*5, kt*5+5). comp 8x8 tile + 3x3 halo in LDS, row stride 12 (2-way
// bank aliasing = free). Weights read with wave-uniform addresses from
// global Wr2 -> s_load/SGPR (SMEM pipe), NOT the DS pipe. Per channel:
// 9 ds_read + 45 v_fmac (SGPR weight operand).
__global__ __launch_bounds__(256, 5) void k2_enc(const float* __restrict__ be,
                                                 float* __restrict__ ws) {
    __shared__ __align__(16) float compT[64 * 120];  // 30720 B
    int b    = blockIdx.x;
    int tile = b & 255;                              // low bits: same-tile
    int kt   = b >> 8;                               // 0..4, siblings same XCD
    int n = tile >> 6, th = (tile >> 3) & 7, tw = tile & 7;
    int h0 = th * 8, w0 = tw * 8;
    int tid = threadIdx.x;

    const float* compn = ws + COMP_F + (size_t)n * 64 * CSTR;
    // stage comp halo tile: compT[c*120 + r*12 + q] = comp[c][h0+r][w0+q]
    for (int e = tid; e < 6400; e += 256) {
        int c = e / 100, rq = e % 100, r = rq / 10, q = rq % 10;
        compT[c * 120 + r * 12 + q] =
            compn[(size_t)c * CSTR + (h0 + r) * 66 + (w0 + q)];
    }
    __syncthreads();

    int lane = tid & 63;
    int ij   = __builtin_amdgcn_readfirstlane(tid >> 6);  // force scalar
    int py = lane >> 3, pxx = lane & 7;

    const float* wb = ws + WR_F + (size_t)((ij * 5 + kt) * 64) * 48;

    float acc[5];
#pragma unroll
    for (int kk = 0; kk < 5; ++kk) acc[kk] = be[4 * (kt * 5 + kk) + ij];

#pragma unroll 2
    for (int c = 0; c < 64; ++c) {
        const float* cp = compT + c * 120 + py * 12 + pxx;
        float cv[9];
#pragma unroll
        for (int dy = 0; dy < 3; ++dy)
#pragma unroll
            for (int dx = 0; dx < 3; ++dx)
                cv[dy * 3 + dx] = cp[dy * 12 + dx];
        const float* w = wb + c * 48;                // uniform -> s_load
#pragma unroll
        for (int q = 0; q < 9; ++q) {
            float v = cv[q];
#pragma unroll
            for (int kk = 0; kk < 5; ++kk)
                acc[kk] += v * w[q * 5 + kk];        // v_fmac v, s, v
        }
    }

    float* lp = ws + LOG_F +
                (size_t)(n * 4096 + (h0 + py) * 64 + (w0 + pxx)) * 100 + ij;
#pragma unroll
    for (int kk = 0; kk < 5; ++kk) lp[4 * (kt * 5 + kk)] = acc[kk];
}

// ---------------- K3 v2: softmax (in-reg) + reassembly ------------------
// grid 1024 x 256thr: b = cchunk*64 + tile. 16x16 px tile, 16-c chunk.
// x tile in LDS as [cg8][r20][q20][2] (channel pairs innermost, row stride
// 42 words): one ds_read_b64 per tap serves 2 channels, lanes contiguous
// 8B (conflict-free quarter-wave pattern), tap offsets are immediates.
// launch_bounds (256,3): 170-VGPR cap -- holds mk[25] (100 VGPR) + accs
// without spilling (the (256,4)=64-VGPR variant spilled 490MB/dispatch).
__global__ __launch_bounds__(256, 3) void k3_out(const float* __restrict__ x,
                                                 const float* __restrict__ ws,
                                                 float* __restrict__ out) {
    __shared__ __align__(16) float xt[8 * 20 * 42];  // 26880 B
    int b      = blockIdx.x;
    int tile   = b & 63;
    int cchunk = b >> 6;
    int n = tile >> 4, ty0 = ((tile >> 2) & 3) * 16, tx0 = (tile & 3) * 16;
    int c0 = cchunk * 16;

    int py = threadIdx.x >> 4, pxx = threadIdx.x & 15;
    int h = ty0 + py, w = tx0 + pxx;

    // issue logit loads first (independent of staging; overlaps)
    const float* lp = ws + LOG_F + (size_t)(n * 4096 + h * 64 + w) * 100;
    float4 mk[25];
#pragma unroll
    for (int t = 0; t < 25; ++t) mk[t] = ((const float4*)lp)[t];

    // stage x halo tile as float2 (halo col origin tx0-2 is even -> the
    // 20-wide row is 10 aligned float2s, all-or-nothing in bounds).
    const float* xn = x + (size_t)(n * 256 + c0) * 4096;
    for (int e2 = threadIdx.x; e2 < 3200; e2 += 256) {
        int c = e2 / 200, rem = e2 % 200, r = rem / 10, q2 = rem % 10;
        int hh = ty0 + r - 2, ww = tx0 + 2 * q2 - 2;
        float2 v = {0.f, 0.f};
        if (hh >= 0 && hh < 64 && ww >= 0 && ww < 64)
            v = *(const float2*)(xn + (size_t)c * 4096 + hh * 64 + ww);
        int a0 = (c >> 1) * 840 + r * 42 + 4 * q2 + (c & 1);
        xt[a0]     = v.x;
        xt[a0 + 2] = v.y;
    }

    // softmax over the 25 taps, per ij component (recomputed per c-chunk: free)
    float4 mx = mk[0];
#pragma unroll
    for (int t = 1; t < 25; ++t) {
        mx.x = fmaxf(mx.x, mk[t].x); mx.y = fmaxf(mx.y, mk[t].y);
        mx.z = fmaxf(mx.z, mk[t].z); mx.w = fmaxf(mx.w, mk[t].w);
    }
    float4 sm = {0.f, 0.f, 0.f, 0.f};
#pragma unroll
    for (int t = 0; t < 25; ++t) {
        mk[t].x = __expf(mk[t].x - mx.x); sm.x += mk[t].x;
        mk[t].y = __expf(mk[t].y - mx.y); sm.y += mk[t].y;
        mk[t].z = __expf(mk[t].z - mx.z); sm.z += mk[t].z;
        mk[t].w = __expf(mk[t].w - mx.w); sm.w += mk[t].w;
    }
    float4 iv = {1.f / sm.x, 1.f / sm.y, 1.f / sm.z, 1.f / sm.w};
#pragma unroll
    for (int t = 0; t < 25; ++t) {
        mk[t].x *= iv.x; mk[t].y *= iv.y; mk[t].z *= iv.z; mk[t].w *= iv.w;
    }
    __syncthreads();

    const float* vb = xt + py * 42 + pxx * 2;
    for (int cg = 0; cg < 8; ++cg) {
        const float* vbc = vb + cg * 840;
        float2 a0 = {0.f, 0.f}, a1 = {0.f, 0.f}, a2 = {0.f, 0.f}, a3 = {0.f, 0.f};
#pragma unroll
        for (int dy = 0; dy < 5; ++dy)
#pragma unroll
            for (int dx = 0; dx < 5; ++dx) {
                int t = dy * 5 + dx;
                float2 v = *(const float2*)(vbc + dy * 42 + dx * 2);
                a0.x += v.x * mk[t].x; a0.y += v.y * mk[t].x;
                a1.x += v.x * mk[t].y; a1.y += v.y * mk[t].y;
                a2.x += v.x * mk[t].z; a2.y += v.y * mk[t].z;
                a3.x += v.x * mk[t].w; a3.y += v.y * mk[t].w;
            }
        int c = cg * 2;
        size_t ob0 = (((size_t)(n * 256 + c0 + c) * 128) + 2 * h) * 128 + 2 * w;
        float2 r0 = {a0.x, a1.x}, r1 = {a2.x, a3.x};
        *(float2*)(out + ob0)       = r0;
        *(float2*)(out + ob0 + 128) = r1;
        size_t ob1 = ob0 + 16384;
        float2 r2 = {a0.y, a1.y}, r3 = {a2.y, a3.y};
        *(float2*)(out + ob1)       = r2;
        *(float2*)(out + ob1 + 128) = r3;
    }
}

// ---------------- Fallback: fused kernel, fp32-only ---------------------
__global__ __launch_bounds__(256) void k_fused(const float* __restrict__ x,
                                               const float* __restrict__ Wc,
                                               const float* __restrict__ bc,
                                               const float* __restrict__ We,
                                               const float* __restrict__ be,
                                               float* __restrict__ out) {
    __shared__ float compS[64 * 101];
    int n = blockIdx.x >> 6, tile = blockIdx.x & 63;
    int ty0 = (tile >> 3) * 8, tx0 = (tile & 7) * 8;
    const float* xn = x + (size_t)n * 256 * 4096;
    {
        int pa = threadIdx.x & 127;
        int ga = __builtin_amdgcn_readfirstlane(threadIdx.x >> 7);
        bool act = pa < 100;
        int ah = ty0 + pa / 10 - 1, aw = tx0 + pa % 10 - 1;
        bool inb = act && ah >= 0 && ah < 64 && aw >= 0 && aw < 64;
        int xoff = ah * 64 + aw;
        float acc[32];
#pragma unroll
        for (int i = 0; i < 32; ++i) acc[i] = 0.f;
        for (int c = 0; c < 256; ++c) {
            float xv = inb ? xn[(size_t)c * 4096 + xoff] : 0.f;
#pragma unroll
            for (int i = 0; i < 32; ++i) acc[i] += xv * Wc[(ga * 32 + i) * 256 + c];
        }
        if (act)
#pragma unroll
            for (int i = 0; i < 32; ++i) {
                int cc = ga * 32 + i;
                compS[cc * 101 + pa] = inb ? acc[i] + bc[cc] : 0.f;
            }
    }
    __syncthreads();
    int px = threadIdx.x & 63;
    int ij = __builtin_amdgcn_readfirstlane(threadIdx.x >> 6);
    int py = px >> 3, pxx = px & 7;
    int h = ty0 + py, w = tx0 + pxx;
    float m[25];
#pragma unroll
    for (int k = 0; k < 25; ++k) m[k] = be[4 * k + ij];
    for (int cc = 0; cc < 64; ++cc) {
        float cv[9];
#pragma unroll
        for (int dy = 0; dy < 3; ++dy)
#pragma unroll
            for (int dx = 0; dx < 3; ++dx)
                cv[dy * 3 + dx] = compS[cc * 101 + (py + dy) * 10 + (pxx + dx)];
        int base = cc * 9;
#pragma unroll
        for (int k = 0; k < 25; ++k) {
            int eb = (4 * k + ij) * 576 + base;
            float s = 0.f;
#pragma unroll
            for (int qb = 0; qb < 9; ++qb) s += cv[qb] * We[eb + qb];
            m[k] += s;
        }
    }
    float mxv = m[0];
#pragma unroll
    for (int k = 1; k < 25; ++k) mxv = fmaxf(mxv, m[k]);
    float ss = 0.f;
#pragma unroll
    for (int k = 0; k < 25; ++k) { m[k] = __expf(m[k] - mxv); ss += m[k]; }
    float inv = 1.f / ss;
#pragma unroll
    for (int k = 0; k < 25; ++k) m[k] *= inv;
    int offs[25];
    unsigned vm = 0;
#pragma unroll
    for (int t = 0; t < 25; ++t) {
        int hh = h + t / 5 - 2, ww = w + t % 5 - 2;
        bool v = hh >= 0 && hh < 64 && ww >= 0 && ww < 64;
        offs[t] = v ? hh * 64 + ww : 0;
        if (v) vm |= 1u << t;
    }
    size_t outp = ((size_t)n * 256 * 128 + (2 * h + (ij >> 1))) * 128 + (2 * w + (ij & 1));
    for (int c = 0; c < 256; ++c) {
        const float* xc = xn + (size_t)c * 4096;
        float sum = 0.f;
#pragma unroll
        for (int t = 0; t < 25; ++t) {
            float v = ((vm >> t) & 1u) ? xc[offs[t]] : 0.f;
            sum += v * m[t];
        }
        out[outp + (size_t)c * 16384] = sum;
    }
}

extern "C" void kernel_launch(void* const* d_in, const int* in_sizes, int n_in,
                              void* d_out, int out_size, void* d_ws, size_t ws_size,
                              hipStream_t stream) {
    const float* x  = (const float*)d_in[0];
    const float* Wc = (const float*)d_in[1];
    const float* bc = (const float*)d_in[2];
    const float* We = (const float*)d_in[3];
    const float* be = (const float*)d_in[4];
    float* out = (float*)d_out;

    if (ws_size >= WS_NEED && d_ws != nullptr) {
        float* ws = (float*)d_ws;
        hipLaunchKernelGGL(k0_wr,   dim3(226),  dim3(256), 0, stream, We, ws);
        hipLaunchKernelGGL(k1_comp, dim3(2048), dim3(64),  0, stream, x, Wc, bc, ws);
        hipLaunchKernelGGL(k2_enc,  dim3(1280), dim3(256), 0, stream, be, ws);
        hipLaunchKernelGGL(k3_out,  dim3(1024), dim3(256), 0, stream, x, ws, out);
    } else {
        hipLaunchKernelGGL(k_fused, dim3(256),  dim3(256), 0, stream,
                           x, Wc, bc, We, be, out);
    }
}

// Round 5
// 186.248 us; speedup vs baseline: 1.5707x; 1.4675x over previous
//
#include <hip/hip_runtime.h>
#include <hip/hip_bf16.h>

// CARAFE fp32 pipeline. x(4,256,64,64), Wc(64,256), bc(64), We(100,64,3,3),
// be(100) -> out(4,256,128,128). SF=2 K=5 G=1 CC=64 EK=3. All I/O fp32.
//
// ws layout (fp32 elements):
//   comp  [4][64][66*66]   zero-padded halo   @ 0          (1,115,136)
//   Wr2   [ij4][kt5][cc64][48]  q*5+kk packed @ 1,115,136  (61,440 of 64,512)
//   logit [16384 px][100]  e = 4k+ij          @ 1,179,648  (1,638,400)
// total 11,272,192 B. Host-gated on ws_size; fallback = fused kernel.
//
// Round 8 (this round): kill the k3 spill STRUCTURALLY. Rounds 6-7 showed
// the launch_bounds min-waves hint caps VGPRs at ~512/(2*arg) on this
// toolchain (arg4->64, arg3->84), both < the ~130 live set -> 150-250MB
// scratch traffic. Fix: remove the 100-reg mk[25] residency entirely.
//   k2s (new): softmax-normalize logits IN PLACE in ws (~13MB R/W, ~5us).
//   k3 v3: taps OUTER, channels inner. Per tap: 1 transient float4 mask
//   load + 8 ds_read_b64 + 32 FMA into float2 A[8][4] (64 resident VGPRs,
//   statically indexed). Live ~100 regs; plain launch_bounds(256), no hint.

#define COMP_F 0
#define WR_F   1115136
#define LOG_F  1179648
#define WS_NEED 11272192ull
#define CSTR 4356  // 66*66 comp per-channel stride

// ---------------- K0: We(100,576) -> Wr2[ij][kt][cc][48] ----------------
// Wr2 row (48 floats, 192B-aligned) holds w[q*5+kk] for one (ij,kt,cc).
__global__ void k0_wr(const float* __restrict__ We, float* __restrict__ ws) {
    int tid = blockIdx.x * blockDim.x + threadIdx.x;
    if (tid >= 4 * 5 * 64 * 45) return;
    int kk = tid % 5;
    int q  = (tid / 5) % 9;
    int cc = (tid / 45) % 64;
    int kt = (tid / 2880) % 5;
    int ij = tid / 14400;
    ws[WR_F + (size_t)(((ij * 5 + kt) * 64 + cc)) * 48 + q * 5 + kk] =
        We[(size_t)(4 * (kt * 5 + kk) + ij) * 576 + cc * 9 + q];
}

// ---------------- K1: 1x1 compressor 256->64, padded comp out ----------
// grid 2048 x 64thr: b = ccg*256 + pw  (same-pixel siblings share XCD L2).
__global__ __launch_bounds__(64) void k1_comp(const float* __restrict__ x,
                                              const float* __restrict__ Wc,
                                              const float* __restrict__ bc,
                                              float* __restrict__ ws) {
    int b   = blockIdx.x;
    int pw  = b & 255;
    int ccg = b >> 8;          // 0..7, wave-uniform
    int n = pw >> 6, h = pw & 63, w = threadIdx.x;
    int cc0 = ccg * 8;

    float acc[8];
#pragma unroll
    for (int u = 0; u < 8; ++u) acc[u] = 0.f;

    const float* xp = x + (size_t)n * 256 * 4096 + h * 64 + w;
#pragma unroll 4
    for (int c = 0; c < 256; ++c) {
        float xv = xp[(size_t)c * 4096];
#pragma unroll
        for (int u = 0; u < 8; ++u)
            acc[u] += xv * Wc[(cc0 + u) * 256 + c];  // uniform -> s_load
    }

    float* compb = ws + COMP_F + (size_t)(n * 64 + cc0) * CSTR;
#pragma unroll
    for (int u = 0; u < 8; ++u) {
        float* cb_ = compb + (size_t)u * CSTR;
        cb_[(h + 1) * 66 + (w + 1)] = acc[u] + bc[cc0 + u];
        // zero halo border (pad=1 of the 3x3 conv)
        if (w < 2) cb_[(h + 1) * 66 + (w ? 65 : 0)] = 0.f;
        if (h == 0)  { cb_[w] = 0.f;           if (w < 2) cb_[64 + w] = 0.f; }
        if (h == 63) { cb_[65 * 66 + w] = 0.f; if (w < 2) cb_[65 * 66 + 64 + w] = 0.f; }
    }
}

// ---------------- K2 v3: 3x3 encoder -> raw logits ----------------------
// grid 1280 = kt*256 + tile; block 256 thr = 4 ij-waves. kt gives k-range
// [kt*5, kt*5+5). comp 8x8 tile + 3x3 halo in LDS, row stride 12 (2-way
// bank aliasing = free). Weights read with wave-uniform addresses from
// global Wr2 -> s_load/SGPR (SMEM pipe), NOT the DS pipe. Per channel:
// 9 ds_read + 45 v_fmac (SGPR weight operand).
__global__ __launch_bounds__(256, 5) void k2_enc(const float* __restrict__ be,
                                                 float* __restrict__ ws) {
    __shared__ __align__(16) float compT[64 * 120];  // 30720 B
    int b    = blockIdx.x;
    int tile = b & 255;                              // low bits: same-tile
    int kt   = b >> 8;                               // 0..4, siblings same XCD
    int n = tile >> 6, th = (tile >> 3) & 7, tw = tile & 7;
    int h0 = th * 8, w0 = tw * 8;
    int tid = threadIdx.x;

    const float* compn = ws + COMP_F + (size_t)n * 64 * CSTR;
    // stage comp halo tile: compT[c*120 + r*12 + q] = comp[c][h0+r][w0+q]
    for (int e = tid; e < 6400; e += 256) {
        int c = e / 100, rq = e % 100, r = rq / 10, q = rq % 10;
        compT[c * 120 + r * 12 + q] =
            compn[(size_t)c * CSTR + (h0 + r) * 66 + (w0 + q)];
    }
    __syncthreads();

    int lane = tid & 63;
    int ij   = __builtin_amdgcn_readfirstlane(tid >> 6);  // force scalar
    int py = lane >> 3, pxx = lane & 7;

    const float* wb = ws + WR_F + (size_t)((ij * 5 + kt) * 64) * 48;

    float acc[5];
#pragma unroll
    for (int kk = 0; kk < 5; ++kk) acc[kk] = be[4 * (kt * 5 + kk) + ij];

#pragma unroll 2
    for (int c = 0; c < 64; ++c) {
        const float* cp = compT + c * 120 + py * 12 + pxx;
        float cv[9];
#pragma unroll
        for (int dy = 0; dy < 3; ++dy)
#pragma unroll
            for (int dx = 0; dx < 3; ++dx)
                cv[dy * 3 + dx] = cp[dy * 12 + dx];
        const float* w = wb + c * 48;                // uniform -> s_load
#pragma unroll
        for (int q = 0; q < 9; ++q) {
            float v = cv[q];
#pragma unroll
            for (int kk = 0; kk < 5; ++kk)
                acc[kk] += v * w[q * 5 + kk];        // v_fmac v, s, v
        }
    }

    float* lp = ws + LOG_F +
                (size_t)(n * 4096 + (h0 + py) * 64 + (w0 + pxx)) * 100 + ij;
#pragma unroll
    for (int kk = 0; kk < 5; ++kk) lp[4 * (kt * 5 + kk)] = acc[kk];
}

// ---------------- K2s: in-place softmax over the 25 taps ----------------
// 65536 threads (grid 256 x 256): thread = (px, ij), ij in low 2 bits so a
// 4-lane group reads 16B contiguous per tap-step. Live set: 25 scalars.
__global__ __launch_bounds__(256) void k2s_sm(float* __restrict__ ws) {
    int tid = blockIdx.x * 256 + threadIdx.x;
    int ij = tid & 3, px = tid >> 2;
    float* p = ws + LOG_F + (size_t)px * 100 + ij;
    float m[25];
#pragma unroll
    for (int k = 0; k < 25; ++k) m[k] = p[4 * k];
    float mx = m[0];
#pragma unroll
    for (int k = 1; k < 25; ++k) mx = fmaxf(mx, m[k]);
    float ss = 0.f;
#pragma unroll
    for (int k = 0; k < 25; ++k) { m[k] = __expf(m[k] - mx); ss += m[k]; }
    float inv = 1.f / ss;
#pragma unroll
    for (int k = 0; k < 25; ++k) p[4 * k] = m[k] * inv;
}

// ---------------- K3 v3: reassembly (masks pre-normalized) --------------
// grid 1024 x 256thr: b = cchunk*64 + tile. 16x16 px tile, 16-c chunk.
// x tile in LDS as [cg8][r20][q20][2] (channel pairs innermost, row stride
// 42 words): one ds_read_b64 per tap serves 2 channels, lanes contiguous
// 8B (conflict-free), tap offsets fold to immediates.
// Taps OUTER, channels inner: mask float4 is a per-tap transient; resident
// state is float2 A[8][4] = 64 VGPRs, statically indexed (no scratch).
// Plain launch_bounds(256) -- no min-waves hint (rounds 6/7: hint caps
// VGPR at ~512/(2*arg) and forced spill).
__global__ __launch_bounds__(256) void k3_out(const float* __restrict__ x,
                                              const float* __restrict__ ws,
                                              float* __restrict__ out) {
    __shared__ __align__(16) float xt[8 * 20 * 42];  // 26880 B
    int b      = blockIdx.x;
    int tile   = b & 63;
    int cchunk = b >> 6;
    int n = tile >> 4, ty0 = ((tile >> 2) & 3) * 16, tx0 = (tile & 3) * 16;
    int c0 = cchunk * 16;

    int py = threadIdx.x >> 4, pxx = threadIdx.x & 15;
    int h = ty0 + py, w = tx0 + pxx;

    // stage x halo tile as float2 (halo col origin tx0-2 is even -> the
    // 20-wide row is 10 aligned float2s, all-or-nothing in bounds).
    const float* xn = x + (size_t)(n * 256 + c0) * 4096;
    for (int e2 = threadIdx.x; e2 < 3200; e2 += 256) {
        int c = e2 / 200, rem = e2 % 200, r = rem / 10, q2 = rem % 10;
        int hh = ty0 + r - 2, ww = tx0 + 2 * q2 - 2;
        float2 v = {0.f, 0.f};
        if (hh >= 0 && hh < 64 && ww >= 0 && ww < 64)
            v = *(const float2*)(xn + (size_t)c * 4096 + hh * 64 + ww);
        int a0 = (c >> 1) * 840 + r * 42 + 4 * q2 + (c & 1);
        xt[a0]     = v.x;
        xt[a0 + 2] = v.y;
    }
    __syncthreads();

    const float* lp = ws + LOG_F + (size_t)(n * 4096 + h * 64 + w) * 100;
    const float* vb = xt + py * 42 + pxx * 2;

    float2 A[8][4];
#pragma unroll
    for (int cg = 0; cg < 8; ++cg)
#pragma unroll
        for (int u = 0; u < 4; ++u) A[cg][u] = {0.f, 0.f};

    for (int dy = 0; dy < 5; ++dy) {
        const float4* mkp = (const float4*)lp + dy * 5;  // 5 taps this row
        const float* vrow = vb + dy * 42;
#pragma unroll
        for (int dx = 0; dx < 5; ++dx) {
            float4 mk = mkp[dx];                         // transient, L2-hot
#pragma unroll
            for (int cg = 0; cg < 8; ++cg) {
                float2 v = *(const float2*)(vrow + cg * 840 + dx * 2);
                A[cg][0].x += v.x * mk.x; A[cg][0].y += v.y * mk.x;
                A[cg][1].x += v.x * mk.y; A[cg][1].y += v.y * mk.y;
                A[cg][2].x += v.x * mk.z; A[cg][2].y += v.y * mk.z;
                A[cg][3].x += v.x * mk.w; A[cg][3].y += v.y * mk.w;
            }
        }
    }

#pragma unroll
    for (int cg = 0; cg < 8; ++cg) {
        int c = cg * 2;
        size_t ob0 = (((size_t)(n * 256 + c0 + c) * 128) + 2 * h) * 128 + 2 * w;
        float2 r0 = {A[cg][0].x, A[cg][1].x}, r1 = {A[cg][2].x, A[cg][3].x};
        *(float2*)(out + ob0)       = r0;
        *(float2*)(out + ob0 + 128) = r1;
        size_t ob1 = ob0 + 16384;
        float2 r2 = {A[cg][0].y, A[cg][1].y}, r3 = {A[cg][2].y, A[cg][3].y};
        *(float2*)(out + ob1)       = r2;
        *(float2*)(out + ob1 + 128) = r3;
    }
}

// ---------------- Fallback: fused kernel, fp32-only ---------------------
__global__ __launch_bounds__(256) void k_fused(const float* __restrict__ x,
                                               const float* __restrict__ Wc,
                                               const float* __restrict__ bc,
                                               const float* __restrict__ We,
                                               const float* __restrict__ be,
                                               float* __restrict__ out) {
    __shared__ float compS[64 * 101];
    int n = blockIdx.x >> 6, tile = blockIdx.x & 63;
    int ty0 = (tile >> 3) * 8, tx0 = (tile & 7) * 8;
    const float* xn = x + (size_t)n * 256 * 4096;
    {
        int pa = threadIdx.x & 127;
        int ga = __builtin_amdgcn_readfirstlane(threadIdx.x >> 7);
        bool act = pa < 100;
        int ah = ty0 + pa / 10 - 1, aw = tx0 + pa % 10 - 1;
        bool inb = act && ah >= 0 && ah < 64 && aw >= 0 && aw < 64;
        int xoff = ah * 64 + aw;
        float acc[32];
#pragma unroll
        for (int i = 0; i < 32; ++i) acc[i] = 0.f;
        for (int c = 0; c < 256; ++c) {
            float xv = inb ? xn[(size_t)c * 4096 + xoff] : 0.f;
#pragma unroll
            for (int i = 0; i < 32; ++i) acc[i] += xv * Wc[(ga * 32 + i) * 256 + c];
        }
        if (act)
#pragma unroll
            for (int i = 0; i < 32; ++i) {
                int cc = ga * 32 + i;
                compS[cc * 101 + pa] = inb ? acc[i] + bc[cc] : 0.f;
            }
    }
    __syncthreads();
    int px = threadIdx.x & 63;
    int ij = __builtin_amdgcn_readfirstlane(threadIdx.x >> 6);
    int py = px >> 3, pxx = px & 7;
    int h = ty0 + py, w = tx0 + pxx;
    float m[25];
#pragma unroll
    for (int k = 0; k < 25; ++k) m[k] = be[4 * k + ij];
    for (int cc = 0; cc < 64; ++cc) {
        float cv[9];
#pragma unroll
        for (int dy = 0; dy < 3; ++dy)
#pragma unroll
            for (int dx = 0; dx < 3; ++dx)
                cv[dy * 3 + dx] = compS[cc * 101 + (py + dy) * 10 + (pxx + dx)];
        int base = cc * 9;
#pragma unroll
        for (int k = 0; k < 25; ++k) {
            int eb = (4 * k + ij) * 576 + base;
            float s = 0.f;
#pragma unroll
            for (int qb = 0; qb < 9; ++qb) s += cv[qb] * We[eb + qb];
            m[k] += s;
        }
    }
    float mxv = m[0];
#pragma unroll
    for (int k = 1; k < 25; ++k) mxv = fmaxf(mxv, m[k]);
    float ss = 0.f;
#pragma unroll
    for (int k = 0; k < 25; ++k) { m[k] = __expf(m[k] - mxv); ss += m[k]; }
    float inv = 1.f / ss;
#pragma unroll
    for (int k = 0; k < 25; ++k) m[k] *= inv;
    int offs[25];
    unsigned vm = 0;
#pragma unroll
    for (int t = 0; t < 25; ++t) {
        int hh = h + t / 5 - 2, ww = w + t % 5 - 2;
        bool v = hh >= 0 && hh < 64 && ww >= 0 && ww < 64;
        offs[t] = v ? hh * 64 + ww : 0;
        if (v) vm |= 1u << t;
    }
    size_t outp = ((size_t)n * 256 * 128 + (2 * h + (ij >> 1))) * 128 + (2 * w + (ij & 1));
    for (int c = 0; c < 256; ++c) {
        const float* xc = xn + (size_t)c * 4096;
        float sum = 0.f;
#pragma unroll
        for (int t = 0; t < 25; ++t) {
            float v = ((vm >> t) & 1u) ? xc[offs[t]] : 0.f;
            sum += v * m[t];
        }
        out[outp + (size_t)c * 16384] = sum;
    }
}

extern "C" void kernel_launch(void* const* d_in, const int* in_sizes, int n_in,
                              void* d_out, int out_size, void* d_ws, size_t ws_size,
                              hipStream_t stream) {
    const float* x  = (const float*)d_in[0];
    const float* Wc = (const float*)d_in[1];
    const float* bc = (const float*)d_in[2];
    const float* We = (const float*)d_in[3];
    const float* be = (const float*)d_in[4];
    float* out = (float*)d_out;

    if (ws_size >= WS_NEED && d_ws != nullptr) {
        float* ws = (float*)d_ws;
        hipLaunchKernelGGL(k0_wr,   dim3(226),  dim3(256), 0, stream, We, ws);
        hipLaunchKernelGGL(k1_comp, dim3(2048), dim3(64),  0, stream, x, Wc, bc, ws);
        hipLaunchKernelGGL(k2_enc,  dim3(1280), dim3(256), 0, stream, be, ws);
        hipLaunchKernelGGL(k2s_sm,  dim3(256),  dim3(256), 0, stream, ws);
        hipLaunchKernelGGL(k3_out,  dim3(1024), dim3(256), 0, stream, x, ws, out);
    } else {
        hipLaunchKernelGGL(k_fused, dim3(256),  dim3(256), 0, stream,
                           x, Wc, bc, We, be, out);
    }
}